// Round 1
// baseline (171.780 us; speedup 1.0000x reference)
//
#include <hip/hip_runtime.h>
#include <math.h>

#define NB 256     // N nodes
#define CH 64      // C input features
#define OUTF 64    // O output features
#define GK 8       // GRID_SIZE + SPLINE_ORDER
#define UIN (CH + OUTF)  // 128 update-KAN input dim

// knot m of the extended grid: (m - SPLINE_ORDER) * h - 1, h = 2/5
__device__ __forceinline__ float knotf(int m) {
    return (float)(m - 3) * 0.4f - 1.0f;
}

__device__ __forceinline__ float silu(float v) {
    return v / (1.0f + __expf(-v));
}

// Cox-de Boor recursion, order 3, 12 knots -> 8 final bases.
__device__ __forceinline__ void bspline8(float r, float* b8) {
    float b[11];
#pragma unroll
    for (int m = 0; m < 11; ++m)
        b[m] = (r >= knotf(m) && r < knotf(m + 1)) ? 1.0f : 0.0f;
#pragma unroll
    for (int k = 1; k <= 3; ++k) {
#pragma unroll
        for (int m = 0; m + k < 11; ++m) {
            float li = 1.0f / (knotf(m + k) - knotf(m));          // compile-time const
            float ri = 1.0f / (knotf(m + k + 1) - knotf(m + 1));  // compile-time const
            b[m] = (r - knotf(m)) * li * b[m] + (knotf(m + k + 1) - r) * ri * b[m + 1];
        }
    }
#pragma unroll
    for (int g = 0; g < GK; ++g) b8[g] = b[g];
}

// msg_val[b,n,o] = kan_linear(x[b,n,:], mw_*)
__global__ __launch_bounds__(64) void msg_kernel(
    const float* __restrict__ x,
    const float* __restrict__ mwb,   // (O, C)
    const float* __restrict__ mws,   // (O, C, GK)
    const float* __restrict__ mwsc,  // (O, C)
    float* __restrict__ msg) {
    const int row = blockIdx.x;        // b*N + n
    const int o = threadIdx.x;         // 0..63

    __shared__ float ssil[CH];
    __shared__ float sb[CH][GK];

    {
        float v = x[row * CH + o];
        ssil[o] = silu(v);
        bspline8(v, sb[o]);
    }
    __syncthreads();

    float acc = 0.0f;
#pragma unroll 4
    for (int c = 0; c < CH; ++c) {
        float s = 0.0f;
#pragma unroll
        for (int g = 0; g < GK; ++g) s += sb[c][g] * mws[(o * CH + c) * GK + g];
        acc += s * mwsc[o * CH + c] + ssil[c] * mwb[o * CH + c];
    }
    msg[row * OUTF + o] = acc;
}

// One block per (b,i). Thread j computes energy(i,j); then softmax, aggregate,
// concat, update-KAN, store out row.
__global__ __launch_bounds__(256) void gat_kernel(
    const float* __restrict__ x,
    const int* __restrict__ adj,
    const float* __restrict__ fwb,   // (1, C)
    const float* __restrict__ fws,   // (1, C, GK)
    const float* __restrict__ fwsc,  // (1, C)
    const float* __restrict__ uwb,   // (O, UIN)
    const float* __restrict__ uws,   // (O, UIN, GK)
    const float* __restrict__ uwsc,  // (O, UIN)
    const float* __restrict__ msg,   // (B, N, O)
    float* __restrict__ out) {
    const int b = blockIdx.x / NB;
    const int i = blockIdx.x % NB;
    const int tid = threadIdx.x;       // == j for the energy phase

    __shared__ float xi[CH];
    __shared__ float sfb[CH];
    __shared__ float sfw[CH][GK];      // fw_spline * fw_scaler
    __shared__ float red[256];
    __shared__ float alpha[NB];
    __shared__ float comb[UIN];
    __shared__ float part[4][OUTF];
    __shared__ float usil[UIN];
    __shared__ float ub[UIN][GK];

    if (tid < CH) {
        float v = x[(b * NB + i) * CH + tid];
        xi[tid] = v;
        comb[tid] = v;
        sfb[tid] = fwb[tid];
        float sc = fwsc[tid];
#pragma unroll
        for (int g = 0; g < GK; ++g) sfw[tid][g] = fws[tid * GK + g] * sc;
    }
    __syncthreads();

    // ---- energy(i, j=tid) ----
    const float* xj = x + (b * NB + tid) * CH;
    float e = 0.0f;
    for (int c = 0; c < CH; ++c) {
        float r = xi[c] - xj[c];
        float bb[GK];
        bspline8(r, bb);
        float s = 0.0f;
#pragma unroll
        for (int g = 0; g < GK; ++g) s += bb[g] * sfw[c][g];
        e += s + silu(r) * sfb[c];
    }
    if (adj[(b * NB + i) * NB + tid] == 0) e = -1e9f;

    // ---- softmax over j ----
    red[tid] = e;
    __syncthreads();
    for (int s = 128; s > 0; s >>= 1) {
        if (tid < s) red[tid] = fmaxf(red[tid], red[tid + s]);
        __syncthreads();
    }
    float mx = red[0];
    __syncthreads();
    float p = __expf(e - mx);
    red[tid] = p;
    __syncthreads();
    for (int s = 128; s > 0; s >>= 1) {
        if (tid < s) red[tid] += red[tid + s];
        __syncthreads();
    }
    float denom = red[0];
    alpha[tid] = p / denom;
    __syncthreads();

    // ---- aggr[o] = sum_j alpha[j] * msg[b,j,o] ----
    {
        const int o = tid & 63;
        const int seg = tid >> 6;
        const float* msgb = msg + b * NB * OUTF;
        float a = 0.0f;
#pragma unroll 4
        for (int j = seg * 64; j < seg * 64 + 64; ++j)
            a += alpha[j] * msgb[j * OUTF + o];
        part[seg][o] = a;
    }
    __syncthreads();
    if (tid < OUTF)
        comb[CH + tid] = part[0][tid] + part[1][tid] + part[2][tid] + part[3][tid];
    __syncthreads();

    // ---- update KAN over 128 combined channels ----
    if (tid < UIN) {
        float v = comb[tid];
        usil[tid] = silu(v);
        bspline8(v, ub[tid]);
    }
    __syncthreads();

    if (tid < OUTF) {
        float acc = 0.0f;
#pragma unroll 2
        for (int c = 0; c < UIN; ++c) {
            float s = 0.0f;
#pragma unroll
            for (int g = 0; g < GK; ++g) s += ub[c][g] * uws[(tid * UIN + c) * GK + g];
            acc += s * uwsc[tid * UIN + c] + usil[c] * uwb[tid * UIN + c];
        }
        out[(b * NB + i) * OUTF + tid] = acc;
    }
}

extern "C" void kernel_launch(void* const* d_in, const int* in_sizes, int n_in,
                              void* d_out, int out_size, void* d_ws, size_t ws_size,
                              hipStream_t stream) {
    const float* x     = (const float*)d_in[0];
    const int*   adj   = (const int*)d_in[1];
    const float* fwb   = (const float*)d_in[2];
    const float* fws   = (const float*)d_in[3];
    const float* fwsc  = (const float*)d_in[4];
    const float* mwb   = (const float*)d_in[5];
    const float* mws   = (const float*)d_in[6];
    const float* mwsc  = (const float*)d_in[7];
    const float* uwb   = (const float*)d_in[8];
    const float* uws   = (const float*)d_in[9];
    const float* uwsc  = (const float*)d_in[10];
    float* out = (float*)d_out;

    const int BN = in_sizes[0] / CH;   // B * N = 512
    float* msg = (float*)d_ws;         // BN * OUTF floats

    msg_kernel<<<BN, 64, 0, stream>>>(x, mwb, mws, mwsc, msg);
    gat_kernel<<<BN, 256, 0, stream>>>(x, adj, fwb, fws, fwsc,
                                       uwb, uws, uwsc, msg, out);
}